// Round 24
// baseline (199.599 us; speedup 1.0000x reference)
//
#include <hip/hip_runtime.h>
#include <hip/hip_bf16.h>
#include <stdint.h>

#define Bn 64
#define Nn 25
#define Cn 128
#define Tn 256
#define EPSC 1e-5f

typedef short bf16x8 __attribute__((ext_vector_type(8)));
typedef float f32x4 __attribute__((ext_vector_type(4)));
typedef int   i32x4 __attribute__((ext_vector_type(4)));

// ws layout
static constexpr size_t X2T_BYTES  = (size_t)Bn * Nn * Tn * Cn * 2;  // 104,857,600
static constexpr size_t WEFF_OFF   = X2T_BYTES;
static constexpr size_t WEFF_BYTES = (size_t)3 * 128 * 128 * 2;      // 98,304
static constexpr size_t EPI_OFF    = WEFF_OFF + WEFF_BYTES;
static constexpr size_t ROWSUM_OFF = EPI_OFF + (size_t)7 * 128 * 4;
static constexpr size_t ZPAGE_OFF  = ROWSUM_OFF + 256;   // 256 B zeros (DMA src for halo)
static constexpr size_t ADJT_OFF   = ZPAGE_OFF + 256;    // adj^T, 25x25 f32
static constexpr size_t WS_NEEDED  = ADJT_OFF + 2560;

__device__ __forceinline__ uint16_t f2bf(float f) {
    uint32_t u = __builtin_bit_cast(uint32_t, f);
    u = (u + 0x7FFFu + ((u >> 16) & 1u)) >> 16;  // RNE
    return (uint16_t)u;
}

// async global->LDS DMA, 16B per lane; LDS dest = wave-uniform base + lane*16
__device__ __forceinline__ void dma16(const void* gsrc, void* ldst) {
    __builtin_amdgcn_global_load_lds(
        (const __attribute__((address_space(1))) unsigned int*)gsrc,
        (__attribute__((address_space(3))) unsigned int*)ldst, 16, 0, 0);
}

// ---------------------------------------------------------------------------
// prep: Weff[k][o][c] = sum_i Wc[o,i,k] * Wg[i,c]  (bf16), epilogue tables,
// rowsum, zero page, adj^T. grid 385 x 128
// ---------------------------------------------------------------------------
__global__ __launch_bounds__(128) void prep_kernel(
    const float* __restrict__ adj, const float* __restrict__ Wg,
    const float* __restrict__ bg,  const float* __restrict__ Wc,
    const float* __restrict__ bc,
    const float* __restrict__ tg,  const float* __restrict__ tb_,
    const float* __restrict__ tm,  const float* __restrict__ tv,
    const float* __restrict__ bng, const float* __restrict__ bnb,
    const float* __restrict__ bnm, const float* __restrict__ bnv,
    uint16_t* __restrict__ weff, float* __restrict__ epi, float* __restrict__ rowsum,
    uint32_t* __restrict__ zpage, float* __restrict__ adjT)
{
    int blk = blockIdx.x;
    int tid = threadIdx.x;
    if (blk < 384) {
        int k = blk >> 7, o = blk & 127;
        float acc = 0.f;
        for (int i = 0; i < 128; ++i) {
            float wc = Wc[(o * 128 + i) * 3 + k];
            acc = fmaf(wc, Wg[i * 128 + tid], acc);
        }
        weff[((size_t)(k * 128 + o)) * 128 + tid] = f2bf(acc);
    } else {
        int o = tid;
        float b0 = 0.f, b1 = 0.f, b2 = 0.f;
        for (int i = 0; i < 128; ++i) {
            float g = bg[i];
            b0 = fmaf(Wc[(o * 128 + i) * 3 + 0], g, b0);
            b1 = fmaf(Wc[(o * 128 + i) * 3 + 1], g, b1);
            b2 = fmaf(Wc[(o * 128 + i) * 3 + 2], g, b2);
        }
        float a1  = tg[o] * rsqrtf(tv[o] + EPSC);
        float c1p = tb_[o] - a1 * tm[o] + a1 * bc[o];
        float a2  = bng[o] * rsqrtf(bnv[o] + EPSC);
        float c2  = bnb[o] - a2 * bnm[o];
        epi[0 * 128 + o] = a1;
        epi[1 * 128 + o] = c1p;
        epi[2 * 128 + o] = a2;
        epi[3 * 128 + o] = c2;
        epi[4 * 128 + o] = a1 * b0;
        epi[5 * 128 + o] = a1 * b1;
        epi[6 * 128 + o] = a1 * b2;
        if (tid < Nn) {
            float s = 0.f;
            for (int n = 0; n < Nn; ++n) s += adj[tid * Nn + n];
            rowsum[tid] = s;
            for (int m = 0; m < Nn; ++m) adjT[tid * Nn + m] = adj[m * Nn + tid];
        }
        if (tid < 64) zpage[tid] = 0u;
    }
}

// ---------------------------------------------------------------------------
// adjmix: x2T[b][m][t][c] (bf16) = sum_n adj[m,n] * x[b][n][c][t]
// 32c x 32t tile; r21 body (5-deep reg-dbuf loads, scalar adjT, pair-per-
// barrier tail) + XCD swizzle: XCD k owns b in {8k..8k+7} (x[b]=3.3MB fits
// its 4MB L2). Bijective (2048%8==0). grid 2048 x 256  [r23 proven, -9us]
// ---------------------------------------------------------------------------
__global__ __launch_bounds__(256) void adjmix_kernel(
    const float* __restrict__ x, const float* __restrict__ adjT,
    uint16_t* __restrict__ x2t)
{
    __shared__ float tr[2][2][32][33];   // [buf][node-half][c][t]

    int bid = blockIdx.x;
    int xcd = bid & 7;
    int j8  = bid >> 3;             // 0..255
    int b   = xcd * 8 + (j8 >> 5);  // 8 consecutive b per XCD
    int rem = j8 & 31;
    int cb = rem >> 3, tb = rem & 7;
    int c0 = cb * 32, t0 = tb * 32;
    int tid = threadIdx.x;

    int cl = tid >> 3;          // 0..31 (channel)
    int t4 = (tid & 7) * 4;     // 0..28 (t, 4 per thread)

    float acc[Nn][4];
#pragma unroll
    for (int m = 0; m < Nn; ++m)
#pragma unroll
        for (int j = 0; j < 4; ++j) acc[m][j] = 0.f;

    const float* xb = x + (((size_t)b * Nn) * Cn + c0 + cl) * Tn + t0 + t4;

    float4 v[2][5];
#pragma unroll
    for (int q = 0; q < 5; ++q)
        v[0][q] = *reinterpret_cast<const float4*>(xb + (size_t)q * Cn * Tn);

#pragma unroll
    for (int ib = 0; ib < 5; ++ib) {
        int nb = ib * 5;
        int s  = ib & 1;
        if (ib < 4) {
#pragma unroll
            for (int q = 0; q < 5; ++q)
                v[s ^ 1][q] = *reinterpret_cast<const float4*>(
                    xb + (size_t)(nb + 5 + q) * Cn * Tn);
        }
#pragma unroll
        for (int q = 0; q < 5; ++q) {
#pragma unroll
            for (int m = 0; m < Nn; ++m) {
                float a = adjT[(nb + q) * Nn + m];   // uniform -> s_load/K$
                acc[m][0] = fmaf(a, v[s][q].x, acc[m][0]);
                acc[m][1] = fmaf(a, v[s][q].y, acc[m][1]);
                acc[m][2] = fmaf(a, v[s][q].z, acc[m][2]);
                acc[m][3] = fmaf(a, v[s][q].w, acc[m][3]);
            }
        }
    }

    // ---- transpose + pack + store: 2 nodes per barrier (r19 proven) ----
    int h    = tid & 127;       // half-lane id
    int half = tid >> 7;        // 0/1 -> node m0+half
    int trow = h >> 2;          // 0..31 (t within tile)
    int cq   = h & 3;           // 0..3  (8-channel quad)

#pragma unroll
    for (int p = 0; p < 13; ++p) {
        int m0  = 2 * p;
        int buf = p & 1;
#pragma unroll
        for (int j = 0; j < 4; ++j) tr[buf][0][cl][t4 + j] = acc[m0][j];
        if (m0 + 1 < Nn) {
#pragma unroll
            for (int j = 0; j < 4; ++j) tr[buf][1][cl][t4 + j] = acc[m0 + 1][j];
        }
        __syncthreads();
        int mm = m0 + half;
        if (mm < Nn) {
            i32x4 u;
#pragma unroll
            for (int k2 = 0; k2 < 4; ++k2) {
                uint32_t lo16 = f2bf(tr[buf][half][cq * 8 + 2 * k2 + 0][trow]);
                uint32_t hi16 = f2bf(tr[buf][half][cq * 8 + 2 * k2 + 1][trow]);
                u[k2] = (int)(lo16 | (hi16 << 16));
            }
            size_t elem = ((size_t)(b * Nn + mm) * Tn + (t0 + trow)) * Cn + c0 + cq * 8;
            *reinterpret_cast<i32x4*>(x2t + elem) = u;
        }
    }
}

// ---------------------------------------------------------------------------
// conv (r16 body — proven): block = (b,m), 8 t-tiles of 32; 2-phase DMA
// pipeline, residual staged via DMA too, weights hoisted (96 VGPR).
// NEW (r24): XCD swizzle ALIGNED WITH ADJMIX — conv block (b,m) runs on
// XCD b/8, the L2 that holds adjmix's x2t[b] writes (the still-resident
// tail becomes L2 hits instead of cross-XCD L3/HBM refetches).
// bid = ((b&7)*25+m)*8 + b/8, bijective (1600 = 200*8).
// LDS 50176 B -> 3 blocks/CU. LAUNCH-BOUNDS RULE: min-waves 2. grid 1600.
// ---------------------------------------------------------------------------
__global__ __launch_bounds__(256, 2) void conv_kernel(
    const uint16_t* __restrict__ x2t, const uint16_t* __restrict__ weff,
    const float* __restrict__ x, const float* __restrict__ epi,
    const float* __restrict__ rowsum, const char* __restrict__ zpage,
    float* __restrict__ out)
{
    constexpr int ROWB = 256;            // bytes per x2t LDS row (128 bf16)
    constexpr int X2TB = 34 * ROWB;      // 8704 B  (x2t part)
    constexpr int RESB = 128 * 128;      // 16384 B (residual: 128 o-rows x 128B)
    constexpr int BUFB = X2TB + RESB;    // 25088 B per buffer
    __shared__ __align__(16) char ldsb[2 * BUFB];   // 50176 B

    int bid0 = blockIdx.x;               // swizzled id
    int xcd   = bid0 & 7;
    int inner = bid0 >> 3;               // 0..199
    int b     = xcd * 8 + inner / Nn;    // aligns with adjmix's b->XCD map
    int m     = inner % Nn;
    int bid   = b * Nn + m;              // logical (b,m) index for addressing

    int tid = threadIdx.x;
    int w  = tid >> 6;
    int l  = tid & 63;
    int lo = l & 15;
    int hi = l >> 4;
    int o0 = w * 32;

    const char* xp2 = (const char*)x2t + (size_t)bid * Tn * Cn * 2;
    const char* xre = (const char*)x   + (size_t)bid * Cn * Tn * 4;  // x[b,m,0,0]
    const short* wp = (const short*)weff;

    // ---- hoist all 24 weight B-frags (96 VGPR) ----
    bf16x8 bw[3][4][2];
#pragma unroll
    for (int kk = 0; kk < 3; ++kk)
#pragma unroll
        for (int cc = 0; cc < 4; ++cc)
#pragma unroll
            for (int f = 0; f < 2; ++f) {
                int o = o0 + f * 16 + lo;
                bw[kk][cc][f] = *reinterpret_cast<const bf16x8*>(
                    wp + ((size_t)(kk * 128 + o)) * 128 + cc * 32 + hi * 8);
            }

    // ---- epilogue tables ----
    float a1[2], c1[2], a2[2], c2v[2], g0[2], g1[2], g2[2];
#pragma unroll
    for (int f = 0; f < 2; ++f) {
        int o = o0 + f * 16 + lo;
        a1[f]  = epi[0 * 128 + o];
        c1[f]  = epi[1 * 128 + o];
        a2[f]  = epi[2 * 128 + o];
        c2v[f] = epi[3 * 128 + o];
        g0[f]  = epi[4 * 128 + o];
        g1[f]  = epi[5 * 128 + o];
        g2[f]  = epi[6 * 128 + o];
    }
    float rs = rowsum[m];
    const size_t obase = (size_t)bid * Cn;

    // ---- stage tile it into buffer:
    //   x2t rows it*32-1 .. it*32+32 (34 rows, halo via zpage), src-swizzled
    //   residual x[b,m, 0..127, it*32..+32) (128 rows x 128B), src-swizzled
    auto stage = [&](int it, int bufByte) {
        int t0 = it * 32;
        // x2t part: 8 wave-ops + half-op (rows 0..33)
#pragma unroll
        for (int oi = 0; oi < 2; ++oi) {
            int rowbase = (w + oi * 4) * 4;
            int r  = rowbase + (l >> 4);
            int cg = l & 15;
            int gt = t0 - 1 + r;
            int sc = cg ^ (r & 7);
            const char* src = (gt >= 0 && gt < Tn)
                ? xp2 + ((size_t)gt * Cn + sc * 8) * 2
                : zpage + sc * 16;
            dma16(src, ldsb + bufByte + rowbase * ROWB);
        }
        if (w == 0 && l < 32) {
            int rowbase = 32;
            int r  = rowbase + (l >> 4);
            int cg = l & 15;
            int gt = t0 - 1 + r;
            int sc = cg ^ (r & 7);
            const char* src = (gt >= 0 && gt < Tn)
                ? xp2 + ((size_t)gt * Cn + sc * 8) * 2
                : zpage + sc * 16;
            dma16(src, ldsb + bufByte + rowbase * ROWB);
        }
        // residual part: 16 wave-ops, 8 o-rows each (128B/row, 8 chunks of 16B)
#pragma unroll
        for (int oi = 0; oi < 4; ++oi) {
            int p    = w * 4 + oi;            // 0..15
            int orow = p * 8 + (l >> 3);      // 0..127
            int cg   = l & 7;
            int sc   = cg ^ (orow & 7);
            const char* src = xre + (size_t)orow * (Tn * 4) + (size_t)t0 * 4 + sc * 16;
            dma16(src, ldsb + bufByte + X2TB + p * 1024);
        }
    };

    int cur = 0;
    stage(0, 0);
    asm volatile("s_waitcnt vmcnt(0)" ::: "memory");
    __syncthreads();

    for (int it = 0; it < 8; ++it) {
        int nxt = cur ^ 1;
        if (it < 7) stage(it + 1, nxt * BUFB);   // prefetch next tile (in flight)

        int tq = it * 32;

        f32x4 acc[2][2];
#pragma unroll
        for (int j = 0; j < 2; ++j)
#pragma unroll
            for (int f = 0; f < 2; ++f) acc[j][f] = (f32x4){0.f, 0.f, 0.f, 0.f};

#pragma unroll
        for (int kk = 0; kk < 3; ++kk)
#pragma unroll
            for (int cc = 0; cc < 4; ++cc) {
                bf16x8 af[2];
#pragma unroll
                for (int j = 0; j < 2; ++j) {
                    int lrow  = j * 16 + lo + kk;        // 0..33
                    int lbyte = cur * BUFB + lrow * ROWB +
                                ((cc * 64 + hi * 16) ^ ((lrow & 7) << 4));
                    af[j] = *reinterpret_cast<const bf16x8*>(ldsb + lbyte);
                }
#pragma unroll
                for (int j = 0; j < 2; ++j)
#pragma unroll
                    for (int f = 0; f < 2; ++f)
                        acc[j][f] = __builtin_amdgcn_mfma_f32_16x16x32_bf16(
                            af[j], bw[kk][cc][f], acc[j][f], 0, 0, 0);
            }

        // fused epilogue: residual from LDS (staged last iteration), f32x4 out
#pragma unroll
        for (int j = 0; j < 2; ++j)
#pragma unroll
            for (int f = 0; f < 2; ++f) {
                int o    = o0 + f * 16 + lo;
                int tb4  = tq + j * 16 + hi * 4;
                int rbyte = cur * BUFB + X2TB + o * 128 +
                            ((j * 64 + hi * 16) ^ ((o & 7) << 4));
                f32x4 r4 = *reinterpret_cast<const f32x4*>(ldsb + rbyte);
                f32x4 ov;
#pragma unroll
                for (int qq = 0; qq < 4; ++qq) {
                    int t = tb4 + qq;
                    float gbv = g1[f];
                    if (t > 0)      gbv += g0[f];
                    if (t < Tn - 1) gbv += g2[f];
                    float z = fmaxf(fmaf(a1[f], acc[j][f][qq], fmaf(rs, gbv, c1[f])), 0.f);
                    ov[qq] = fmaxf(fmaf(a2[f], z + r4[qq], c2v[f]), 0.f);
                }
                *reinterpret_cast<f32x4*>(out + (obase + o) * Tn + tb4) = ov;
            }

        asm volatile("s_waitcnt vmcnt(0)" ::: "memory");
        __syncthreads();
        cur = nxt;
    }
}

// ---------------------------------------------------------------------------
extern "C" void kernel_launch(void* const* d_in, const int* in_sizes, int n_in,
                              void* d_out, int out_size, void* d_ws, size_t ws_size,
                              hipStream_t stream) {
    const float* x    = (const float*)d_in[0];
    const float* adj  = (const float*)d_in[1];
    const float* Wg   = (const float*)d_in[2];
    const float* bg   = (const float*)d_in[3];
    const float* Wc   = (const float*)d_in[4];
    const float* bc   = (const float*)d_in[5];
    const float* tg   = (const float*)d_in[6];
    const float* tb_  = (const float*)d_in[7];
    const float* tm   = (const float*)d_in[8];
    const float* tv   = (const float*)d_in[9];
    const float* bng  = (const float*)d_in[10];
    const float* bnb  = (const float*)d_in[11];
    const float* bnm  = (const float*)d_in[12];
    const float* bnv  = (const float*)d_in[13];

    if (ws_size < WS_NEEDED) return;

    char* ws = (char*)d_ws;
    uint16_t* x2t    = (uint16_t*)ws;
    uint16_t* weff   = (uint16_t*)(ws + WEFF_OFF);
    float*    epi    = (float*)(ws + EPI_OFF);
    float*    rowsum = (float*)(ws + ROWSUM_OFF);
    char*     zpage  = ws + ZPAGE_OFF;
    float*    adjT   = (float*)(ws + ADJT_OFF);
    float*    out    = (float*)d_out;

    prep_kernel<<<385, 128, 0, stream>>>(adj, Wg, bg, Wc, bc, tg, tb_, tm, tv,
                                         bng, bnb, bnm, bnv, weff, epi, rowsum,
                                         (uint32_t*)zpage, adjT);
    adjmix_kernel<<<2048, 256, 0, stream>>>(x, adjT, x2t);
    conv_kernel<<<Bn * Nn, 256, 0, stream>>>(x2t, weff, x, epi, rowsum, zpage, out);
}

// Round 25
// 188.627 us; speedup vs baseline: 1.0582x; 1.0582x over previous
//
#include <hip/hip_runtime.h>
#include <hip/hip_bf16.h>
#include <stdint.h>

#define Bn 64
#define Nn 25
#define Cn 128
#define Tn 256
#define EPSC 1e-5f

typedef short bf16x8 __attribute__((ext_vector_type(8)));
typedef float f32x4 __attribute__((ext_vector_type(4)));
typedef int   i32x4 __attribute__((ext_vector_type(4)));

// ws layout
static constexpr size_t X2T_BYTES  = (size_t)Bn * Nn * Tn * Cn * 2;  // 104,857,600
static constexpr size_t WEFF_OFF   = X2T_BYTES;
static constexpr size_t WEFF_BYTES = (size_t)3 * 128 * 128 * 2;      // 98,304
static constexpr size_t EPI_OFF    = WEFF_OFF + WEFF_BYTES;
static constexpr size_t ROWSUM_OFF = EPI_OFF + (size_t)7 * 128 * 4;
static constexpr size_t ZPAGE_OFF  = ROWSUM_OFF + 256;   // 256 B zeros (DMA src for halo)
static constexpr size_t ADJT_OFF   = ZPAGE_OFF + 256;    // adj^T, 25x25 f32
static constexpr size_t WS_NEEDED  = ADJT_OFF + 2560;

__device__ __forceinline__ uint16_t f2bf(float f) {
    uint32_t u = __builtin_bit_cast(uint32_t, f);
    u = (u + 0x7FFFu + ((u >> 16) & 1u)) >> 16;  // RNE
    return (uint16_t)u;
}

// async global->LDS DMA, 16B per lane; LDS dest = wave-uniform base + lane*16
__device__ __forceinline__ void dma16(const void* gsrc, void* ldst) {
    __builtin_amdgcn_global_load_lds(
        (const __attribute__((address_space(1))) unsigned int*)gsrc,
        (__attribute__((address_space(3))) unsigned int*)ldst, 16, 0, 0);
}

// ---------------------------------------------------------------------------
// prep: Weff[k][o][c] = sum_i Wc[o,i,k] * Wg[i,c]  (bf16), epilogue tables,
// rowsum, zero page, adj^T. grid 385 x 128
// ---------------------------------------------------------------------------
__global__ __launch_bounds__(128) void prep_kernel(
    const float* __restrict__ adj, const float* __restrict__ Wg,
    const float* __restrict__ bg,  const float* __restrict__ Wc,
    const float* __restrict__ bc,
    const float* __restrict__ tg,  const float* __restrict__ tb_,
    const float* __restrict__ tm,  const float* __restrict__ tv,
    const float* __restrict__ bng, const float* __restrict__ bnb,
    const float* __restrict__ bnm, const float* __restrict__ bnv,
    uint16_t* __restrict__ weff, float* __restrict__ epi, float* __restrict__ rowsum,
    uint32_t* __restrict__ zpage, float* __restrict__ adjT)
{
    int blk = blockIdx.x;
    int tid = threadIdx.x;
    if (blk < 384) {
        int k = blk >> 7, o = blk & 127;
        float acc = 0.f;
        for (int i = 0; i < 128; ++i) {
            float wc = Wc[(o * 128 + i) * 3 + k];
            acc = fmaf(wc, Wg[i * 128 + tid], acc);
        }
        weff[((size_t)(k * 128 + o)) * 128 + tid] = f2bf(acc);
    } else {
        int o = tid;
        float b0 = 0.f, b1 = 0.f, b2 = 0.f;
        for (int i = 0; i < 128; ++i) {
            float g = bg[i];
            b0 = fmaf(Wc[(o * 128 + i) * 3 + 0], g, b0);
            b1 = fmaf(Wc[(o * 128 + i) * 3 + 1], g, b1);
            b2 = fmaf(Wc[(o * 128 + i) * 3 + 2], g, b2);
        }
        float a1  = tg[o] * rsqrtf(tv[o] + EPSC);
        float c1p = tb_[o] - a1 * tm[o] + a1 * bc[o];
        float a2  = bng[o] * rsqrtf(bnv[o] + EPSC);
        float c2  = bnb[o] - a2 * bnm[o];
        epi[0 * 128 + o] = a1;
        epi[1 * 128 + o] = c1p;
        epi[2 * 128 + o] = a2;
        epi[3 * 128 + o] = c2;
        epi[4 * 128 + o] = a1 * b0;
        epi[5 * 128 + o] = a1 * b1;
        epi[6 * 128 + o] = a1 * b2;
        if (tid < Nn) {
            float s = 0.f;
            for (int n = 0; n < Nn; ++n) s += adj[tid * Nn + n];
            rowsum[tid] = s;
            for (int m = 0; m < Nn; ++m) adjT[tid * Nn + m] = adj[m * Nn + tid];
        }
        if (tid < 64) zpage[tid] = 0u;
    }
}

// ---------------------------------------------------------------------------
// adjmix: x2T[b][m][t][c] (bf16) = sum_n adj[m,n] * x[b][n][c][t]
// 32c x 32t tile; r21's proven body (5-deep reg-double-buffered loads,
// scalar adjT, pair-per-barrier tail) + T1 XCD SWIZZLE: the 32 blocks
// sharing b land on ONE XCD (x[b]=3.3MB fits its 4MB L2) instead of
// scattering over all 8 L2s. Bijective (2048%8==0). grid 2048 x 256
// [r23 proven: -9us. Do NOT swizzle conv (r24: +10us regression — no
// cross-dispatch L2 residency at 105MB footprint; clustering serializes.]
// ---------------------------------------------------------------------------
__global__ __launch_bounds__(256) void adjmix_kernel(
    const float* __restrict__ x, const float* __restrict__ adjT,
    uint16_t* __restrict__ x2t)
{
    __shared__ float tr[2][2][32][33];   // [buf][node-half][c][t]

    int bid = blockIdx.x;
    // XCD-aware swizzle: dispatch assigns XCD = bid % 8; keep same-b blocks
    // on the same XCD for L2 reuse of the 3.3MB x[b] slab.
    int xcd = bid & 7;
    int j8  = bid >> 3;             // 0..255
    int b   = xcd * 8 + (j8 >> 5);  // 8 consecutive b per XCD
    int rem = j8 & 31;
    int cb = rem >> 3, tb = rem & 7;
    int c0 = cb * 32, t0 = tb * 32;
    int tid = threadIdx.x;

    int cl = tid >> 3;          // 0..31 (channel)
    int t4 = (tid & 7) * 4;     // 0..28 (t, 4 per thread)

    float acc[Nn][4];
#pragma unroll
    for (int m = 0; m < Nn; ++m)
#pragma unroll
        for (int j = 0; j < 4; ++j) acc[m][j] = 0.f;

    const float* xb = x + (((size_t)b * Nn) * Cn + c0 + cl) * Tn + t0 + t4;

    float4 v[2][5];
#pragma unroll
    for (int q = 0; q < 5; ++q)
        v[0][q] = *reinterpret_cast<const float4*>(xb + (size_t)q * Cn * Tn);

#pragma unroll
    for (int ib = 0; ib < 5; ++ib) {
        int nb = ib * 5;
        int s  = ib & 1;
        if (ib < 4) {
#pragma unroll
            for (int q = 0; q < 5; ++q)
                v[s ^ 1][q] = *reinterpret_cast<const float4*>(
                    xb + (size_t)(nb + 5 + q) * Cn * Tn);
        }
#pragma unroll
        for (int q = 0; q < 5; ++q) {
#pragma unroll
            for (int m = 0; m < Nn; ++m) {
                float a = adjT[(nb + q) * Nn + m];   // uniform -> s_load/K$
                acc[m][0] = fmaf(a, v[s][q].x, acc[m][0]);
                acc[m][1] = fmaf(a, v[s][q].y, acc[m][1]);
                acc[m][2] = fmaf(a, v[s][q].z, acc[m][2]);
                acc[m][3] = fmaf(a, v[s][q].w, acc[m][3]);
            }
        }
    }

    // ---- transpose + pack + store: 2 nodes per barrier (r19 proven) ----
    int h    = tid & 127;       // half-lane id
    int half = tid >> 7;        // 0/1 -> node m0+half
    int trow = h >> 2;          // 0..31 (t within tile)
    int cq   = h & 3;           // 0..3  (8-channel quad)

#pragma unroll
    for (int p = 0; p < 13; ++p) {
        int m0  = 2 * p;
        int buf = p & 1;
#pragma unroll
        for (int j = 0; j < 4; ++j) tr[buf][0][cl][t4 + j] = acc[m0][j];
        if (m0 + 1 < Nn) {
#pragma unroll
            for (int j = 0; j < 4; ++j) tr[buf][1][cl][t4 + j] = acc[m0 + 1][j];
        }
        __syncthreads();
        int mm = m0 + half;
        if (mm < Nn) {
            i32x4 u;
#pragma unroll
            for (int k2 = 0; k2 < 4; ++k2) {
                uint32_t lo16 = f2bf(tr[buf][half][cq * 8 + 2 * k2 + 0][trow]);
                uint32_t hi16 = f2bf(tr[buf][half][cq * 8 + 2 * k2 + 1][trow]);
                u[k2] = (int)(lo16 | (hi16 << 16));
            }
            size_t elem = ((size_t)(b * Nn + mm) * Tn + (t0 + trow)) * Cn + c0 + cq * 8;
            *reinterpret_cast<i32x4*>(x2t + elem) = u;
        }
    }
}

// ---------------------------------------------------------------------------
// conv (r16 verbatim — proven): block = (b,m), 8 t-tiles of 32;
// 2-phase DMA pipeline with the RESIDUAL tile also staged via global_load_lds
// (no mid-iteration flat loads). Weights hoisted (96 VGPR). DEFAULT dispatch
// (r24 proved XCD-clustering hurts conv).
// LDS 2 x (8704 + 16384) = 50176 B -> 3 blocks/CU.
// LAUNCH-BOUNDS RULE (r4/r6/r7): must stay min-waves 2. grid 1600.
// ---------------------------------------------------------------------------
__global__ __launch_bounds__(256, 2) void conv_kernel(
    const uint16_t* __restrict__ x2t, const uint16_t* __restrict__ weff,
    const float* __restrict__ x, const float* __restrict__ epi,
    const float* __restrict__ rowsum, const char* __restrict__ zpage,
    float* __restrict__ out)
{
    constexpr int ROWB = 256;            // bytes per x2t LDS row (128 bf16)
    constexpr int X2TB = 34 * ROWB;      // 8704 B  (x2t part)
    constexpr int RESB = 128 * 128;      // 16384 B (residual: 128 o-rows x 128B)
    constexpr int BUFB = X2TB + RESB;    // 25088 B per buffer
    __shared__ __align__(16) char ldsb[2 * BUFB];   // 50176 B

    int bid = blockIdx.x;                // b*Nn + m, 1600 blocks
    int m   = bid % Nn;

    int tid = threadIdx.x;
    int w  = tid >> 6;
    int l  = tid & 63;
    int lo = l & 15;
    int hi = l >> 4;
    int o0 = w * 32;

    const char* xp2 = (const char*)x2t + (size_t)bid * Tn * Cn * 2;
    const char* xre = (const char*)x   + (size_t)bid * Cn * Tn * 4;  // x[b,m,0,0]
    const short* wp = (const short*)weff;

    // ---- hoist all 24 weight B-frags (96 VGPR) ----
    bf16x8 bw[3][4][2];
#pragma unroll
    for (int kk = 0; kk < 3; ++kk)
#pragma unroll
        for (int cc = 0; cc < 4; ++cc)
#pragma unroll
            for (int f = 0; f < 2; ++f) {
                int o = o0 + f * 16 + lo;
                bw[kk][cc][f] = *reinterpret_cast<const bf16x8*>(
                    wp + ((size_t)(kk * 128 + o)) * 128 + cc * 32 + hi * 8);
            }

    // ---- epilogue tables ----
    float a1[2], c1[2], a2[2], c2v[2], g0[2], g1[2], g2[2];
#pragma unroll
    for (int f = 0; f < 2; ++f) {
        int o = o0 + f * 16 + lo;
        a1[f]  = epi[0 * 128 + o];
        c1[f]  = epi[1 * 128 + o];
        a2[f]  = epi[2 * 128 + o];
        c2v[f] = epi[3 * 128 + o];
        g0[f]  = epi[4 * 128 + o];
        g1[f]  = epi[5 * 128 + o];
        g2[f]  = epi[6 * 128 + o];
    }
    float rs = rowsum[m];
    const size_t obase = (size_t)bid * Cn;

    // ---- stage tile it into buffer:
    //   x2t rows it*32-1 .. it*32+32 (34 rows, halo via zpage), src-swizzled
    //   residual x[b,m, 0..127, it*32..+32) (128 rows x 128B), src-swizzled
    auto stage = [&](int it, int bufByte) {
        int t0 = it * 32;
        // x2t part: 8 wave-ops + half-op (rows 0..33)
#pragma unroll
        for (int oi = 0; oi < 2; ++oi) {
            int rowbase = (w + oi * 4) * 4;
            int r  = rowbase + (l >> 4);
            int cg = l & 15;
            int gt = t0 - 1 + r;
            int sc = cg ^ (r & 7);
            const char* src = (gt >= 0 && gt < Tn)
                ? xp2 + ((size_t)gt * Cn + sc * 8) * 2
                : zpage + sc * 16;
            dma16(src, ldsb + bufByte + rowbase * ROWB);
        }
        if (w == 0 && l < 32) {
            int rowbase = 32;
            int r  = rowbase + (l >> 4);
            int cg = l & 15;
            int gt = t0 - 1 + r;
            int sc = cg ^ (r & 7);
            const char* src = (gt >= 0 && gt < Tn)
                ? xp2 + ((size_t)gt * Cn + sc * 8) * 2
                : zpage + sc * 16;
            dma16(src, ldsb + bufByte + rowbase * ROWB);
        }
        // residual part: 16 wave-ops, 8 o-rows each (128B/row, 8 chunks of 16B)
#pragma unroll
        for (int oi = 0; oi < 4; ++oi) {
            int p    = w * 4 + oi;            // 0..15
            int orow = p * 8 + (l >> 3);      // 0..127
            int cg   = l & 7;
            int sc   = cg ^ (orow & 7);
            const char* src = xre + (size_t)orow * (Tn * 4) + (size_t)t0 * 4 + sc * 16;
            dma16(src, ldsb + bufByte + X2TB + p * 1024);
        }
    };

    int cur = 0;
    stage(0, 0);
    asm volatile("s_waitcnt vmcnt(0)" ::: "memory");
    __syncthreads();

    for (int it = 0; it < 8; ++it) {
        int nxt = cur ^ 1;
        if (it < 7) stage(it + 1, nxt * BUFB);   // prefetch next tile (in flight)

        int tq = it * 32;

        f32x4 acc[2][2];
#pragma unroll
        for (int j = 0; j < 2; ++j)
#pragma unroll
            for (int f = 0; f < 2; ++f) acc[j][f] = (f32x4){0.f, 0.f, 0.f, 0.f};

#pragma unroll
        for (int kk = 0; kk < 3; ++kk)
#pragma unroll
            for (int cc = 0; cc < 4; ++cc) {
                bf16x8 af[2];
#pragma unroll
                for (int j = 0; j < 2; ++j) {
                    int lrow  = j * 16 + lo + kk;        // 0..33
                    int lbyte = cur * BUFB + lrow * ROWB +
                                ((cc * 64 + hi * 16) ^ ((lrow & 7) << 4));
                    af[j] = *reinterpret_cast<const bf16x8*>(ldsb + lbyte);
                }
#pragma unroll
                for (int j = 0; j < 2; ++j)
#pragma unroll
                    for (int f = 0; f < 2; ++f)
                        acc[j][f] = __builtin_amdgcn_mfma_f32_16x16x32_bf16(
                            af[j], bw[kk][cc][f], acc[j][f], 0, 0, 0);
            }

        // fused epilogue: residual from LDS (staged last iteration), f32x4 out
#pragma unroll
        for (int j = 0; j < 2; ++j)
#pragma unroll
            for (int f = 0; f < 2; ++f) {
                int o    = o0 + f * 16 + lo;
                int tb4  = tq + j * 16 + hi * 4;
                int rbyte = cur * BUFB + X2TB + o * 128 +
                            ((j * 64 + hi * 16) ^ ((o & 7) << 4));
                f32x4 r4 = *reinterpret_cast<const f32x4*>(ldsb + rbyte);
                f32x4 ov;
#pragma unroll
                for (int qq = 0; qq < 4; ++qq) {
                    int t = tb4 + qq;
                    float gbv = g1[f];
                    if (t > 0)      gbv += g0[f];
                    if (t < Tn - 1) gbv += g2[f];
                    float z = fmaxf(fmaf(a1[f], acc[j][f][qq], fmaf(rs, gbv, c1[f])), 0.f);
                    ov[qq] = fmaxf(fmaf(a2[f], z + r4[qq], c2v[f]), 0.f);
                }
                *reinterpret_cast<f32x4*>(out + (obase + o) * Tn + tb4) = ov;
            }

        asm volatile("s_waitcnt vmcnt(0)" ::: "memory");
        __syncthreads();
        cur = nxt;
    }
}

// ---------------------------------------------------------------------------
extern "C" void kernel_launch(void* const* d_in, const int* in_sizes, int n_in,
                              void* d_out, int out_size, void* d_ws, size_t ws_size,
                              hipStream_t stream) {
    const float* x    = (const float*)d_in[0];
    const float* adj  = (const float*)d_in[1];
    const float* Wg   = (const float*)d_in[2];
    const float* bg   = (const float*)d_in[3];
    const float* Wc   = (const float*)d_in[4];
    const float* bc   = (const float*)d_in[5];
    const float* tg   = (const float*)d_in[6];
    const float* tb_  = (const float*)d_in[7];
    const float* tm   = (const float*)d_in[8];
    const float* tv   = (const float*)d_in[9];
    const float* bng  = (const float*)d_in[10];
    const float* bnb  = (const float*)d_in[11];
    const float* bnm  = (const float*)d_in[12];
    const float* bnv  = (const float*)d_in[13];

    if (ws_size < WS_NEEDED) return;

    char* ws = (char*)d_ws;
    uint16_t* x2t    = (uint16_t*)ws;
    uint16_t* weff   = (uint16_t*)(ws + WEFF_OFF);
    float*    epi    = (float*)(ws + EPI_OFF);
    float*    rowsum = (float*)(ws + ROWSUM_OFF);
    char*     zpage  = ws + ZPAGE_OFF;
    float*    adjT   = (float*)(ws + ADJT_OFF);
    float*    out    = (float*)d_out;

    prep_kernel<<<385, 128, 0, stream>>>(adj, Wg, bg, Wc, bc, tg, tb_, tm, tv,
                                         bng, bnb, bnm, bnv, weff, epi, rowsum,
                                         (uint32_t*)zpage, adjT);
    adjmix_kernel<<<2048, 256, 0, stream>>>(x, adjT, x2t);
    conv_kernel<<<Bn * Nn, 256, 0, stream>>>(x2t, weff, x, epi, rowsum, zpage, out);
}